// Round 7
// baseline (406.691 us; speedup 1.0000x reference)
//
#include <hip/hip_runtime.h>
#include <math.h>

#define N_NODES 20000
#define N_EDGES 320000
#define DIM_IN 128
#define HID 64
#define HEADS 4
#define LAYERS 3
#define GRAPHS 128
#define QSS 320    // stored f32 cols: 256 q | 64 s

typedef unsigned short ushort;
typedef ushort ushort8 __attribute__((ext_vector_type(8)));
typedef ushort ushort4v __attribute__((ext_vector_type(4)));
typedef short short8 __attribute__((ext_vector_type(8)));
typedef float f32x4 __attribute__((ext_vector_type(4)));

__device__ __forceinline__ float bf2f(ushort u) {
    return __uint_as_float(((unsigned int)u) << 16);
}
__device__ __forceinline__ ushort f2bf(float f) {
    unsigned int b = __float_as_uint(f);
    return (ushort)((b + 0x7FFFu + ((b >> 16) & 1u)) >> 16);
}

// ---------------- CSR build ----------------

__global__ void hist_kernel(const int* __restrict__ dst, int* __restrict__ counts, int n) {
    int e = blockIdx.x * 256 + threadIdx.x;
    if (e < n) atomicAdd(&counts[dst[e]], 1);
}

__global__ __launch_bounds__(256) void blocksum_kernel(const int* __restrict__ counts,
                                                       int* __restrict__ bsum, int n) {
    int i = blockIdx.x * 256 + threadIdx.x;
    int v = (i < n) ? counts[i] : 0;
    int lane = threadIdx.x & 63, wave = threadIdx.x >> 6;
#pragma unroll
    for (int off = 32; off >= 1; off >>= 1) v += __shfl_xor(v, off);
    __shared__ int ws[4];
    if (lane == 0) ws[wave] = v;
    __syncthreads();
    if (threadIdx.x == 0) bsum[blockIdx.x] = ws[0] + ws[1] + ws[2] + ws[3];
}

__global__ __launch_bounds__(128) void scanb_kernel(const int* __restrict__ bsum,
                                                    int* __restrict__ bexcl, int nb) {
    int tid = threadIdx.x;
    int v = (tid < nb) ? bsum[tid] : 0;
    int lane = tid & 63, wave = tid >> 6;
    int s = v;
#pragma unroll
    for (int off = 1; off < 64; off <<= 1) {
        int t = __shfl_up(s, off);
        if (lane >= off) s += t;
    }
    __shared__ int w0sum;
    if (tid == 63) w0sum = s;
    __syncthreads();
    int excl = s - v + (wave ? w0sum : 0);
    if (tid < nb) bexcl[tid] = excl;
}

__global__ __launch_bounds__(256) void expand_kernel(const int* __restrict__ counts,
                                                     const int* __restrict__ bexcl,
                                                     int* __restrict__ offs,
                                                     int* __restrict__ cursor, int n) {
    int i = blockIdx.x * 256 + threadIdx.x;
    int v = (i < n) ? counts[i] : 0;
    int lane = threadIdx.x & 63, wave = threadIdx.x >> 6;
    int s = v;
#pragma unroll
    for (int off = 1; off < 64; off <<= 1) {
        int t = __shfl_up(s, off);
        if (lane >= off) s += t;
    }
    __shared__ int wsum[4];
    if (lane == 63) wsum[wave] = s;
    __syncthreads();
    int add = bexcl[blockIdx.x];
    for (int w = 0; w < wave; ++w) add += wsum[w];
    int excl = add + s - v;
    if (i < n) { offs[i] = excl; cursor[i] = excl; }
    if (i == 0) offs[n] = N_EDGES;
}

__global__ void scatter_kernel(const int* __restrict__ src, const int* __restrict__ dst,
                               int* __restrict__ cursor, int* __restrict__ csr, int n) {
    int e = blockIdx.x * 256 + threadIdx.x;
    if (e < n) {
        int d = dst[e];
        int pos = atomicAdd(&cursor[d], 1);
        csr[pos] = src[e];
    }
}

// ---------------- one-shot weight convert (all layers + input linear) ----------------
// Wt3[l][832][64] bf16, col j of layer l:
//   j <256   : q col j
//   256..767 : permuted k/v col — pout=j-256; isv=(pout>>2)&1; low2=pout&3; g=pout>>3;
//              srccol=(g>>4)*64+(g&15)*4+low2; from Wk (isv=0) or Wv (isv=1)
//   >=768    : s col j-768
// bias3[l][832] matches. Wlt[64][128] bf16 from linW.

__global__ __launch_bounds__(256) void wcvt_all_kernel(
        const float* __restrict__ Wq, const float* __restrict__ bq,
        const float* __restrict__ Wk, const float* __restrict__ bk,
        const float* __restrict__ Wv, const float* __restrict__ bv,
        const float* __restrict__ Ws, const float* __restrict__ bs,
        const float* __restrict__ linW,
        ushort* __restrict__ Wt3, float* __restrict__ bias3,
        ushort* __restrict__ Wlt) {
    const int PER = 832 * 64;
    int idx = blockIdx.x * 256 + threadIdx.x;
    if (idx < 3 * PER) {
        int l = idx / PER;
        int r = idx - l * PER;
        int j = r >> 6, k = r & 63;
        const float* Wq_l = Wq + (size_t)l * HID * 256;
        const float* Wk_l = Wk + (size_t)l * HID * 256;
        const float* Wv_l = Wv + (size_t)l * HID * 256;
        const float* Ws_l = Ws + (size_t)l * HID * 64;
        float w;
        if (j < 256) {
            w = Wq_l[(size_t)k * 256 + j];
        } else if (j < 768) {
            int pout = j - 256;
            int isv = (pout >> 2) & 1;
            int low2 = pout & 3;
            int g = pout >> 3;
            int srccol = (g >> 4) * 64 + (g & 15) * 4 + low2;
            w = isv ? Wv_l[(size_t)k * 256 + srccol] : Wk_l[(size_t)k * 256 + srccol];
        } else {
            w = Ws_l[(size_t)k * 64 + (j - 768)];
        }
        Wt3[idx] = f2bf(w);
    } else {
        int idx2 = idx - 3 * PER;
        if (idx2 < 64 * DIM_IN) {
            int col = idx2 >> 7, k = idx2 & 127;
            Wlt[idx2] = f2bf(linW[(size_t)k * HID + col]);
        }
    }
    if (idx < 3 * 832) {
        int l = idx / 832, j = idx - l * 832;
        float b;
        if (j < 256) {
            b = bq[l * 256 + j];
        } else if (j < 768) {
            int pout = j - 256;
            int isv = (pout >> 2) & 1;
            int low2 = pout & 3;
            int g = pout >> 3;
            int srccol = (g >> 4) * 64 + (g & 15) * 4 + low2;
            b = isv ? bv[l * 256 + srccol] : bk[l * 256 + srccol];
        } else {
            b = bs[l * 64 + (j - 768)];
        }
        bias3[idx] = b;
    }
}

// ---------------- input linear via MFMA (operand-swapped): h0 = x @ linW + linb ----------------
// mfma(A=Wlt-frag, B=x-frag): D row index = out col j, D col index = x row.
// Lane l: x-row = r0 + (l&15); per tile t, j = 16t + (l>>4)*4 + [0..4) -> float4 store.

__global__ __launch_bounds__(256) void lin_kernel(const float* __restrict__ x,
                                                  const ushort* __restrict__ Wlt,
                                                  const float* __restrict__ lb,
                                                  float* __restrict__ h0) {
    int tid = threadIdx.x;
    int w = tid >> 6, l = tid & 63;
    int r0 = blockIdx.x * 64 + w * 16;
    int row = r0 + (l & 15);
    int rowc = (row < N_NODES) ? row : (N_NODES - 1);

    short8 a[4];
#pragma unroll
    for (int kc = 0; kc < 4; ++kc) {
        const float* xp = x + (size_t)rowc * DIM_IN + kc * 32 + (l >> 4) * 8;
        float4 f0 = *(const float4*)xp;
        float4 f1 = *(const float4*)(xp + 4);
        ushort8 u;
        u[0] = f2bf(f0.x); u[1] = f2bf(f0.y); u[2] = f2bf(f0.z); u[3] = f2bf(f0.w);
        u[4] = f2bf(f1.x); u[5] = f2bf(f1.y); u[6] = f2bf(f1.z); u[7] = f2bf(f1.w);
        a[kc] = __builtin_bit_cast(short8, u);
    }

    f32x4 acc[4];
#pragma unroll
    for (int t = 0; t < 4; ++t) acc[t] = (f32x4){0.f, 0.f, 0.f, 0.f};

    const ushort* wb = Wlt + (size_t)(l & 15) * DIM_IN + (l >> 4) * 8;
#pragma unroll
    for (int t = 0; t < 4; ++t) {
#pragma unroll
        for (int kc = 0; kc < 4; ++kc) {
            short8 b = *(const short8*)(wb + (size_t)t * 16 * DIM_IN + kc * 32);
            // swapped: A = weight frag, B = x frag
            acc[t] = __builtin_amdgcn_mfma_f32_16x16x32_bf16(b, a[kc], acc[t], 0, 0, 0);
        }
    }

    if (row < N_NODES) {
#pragma unroll
        for (int t = 0; t < 4; ++t) {
            int j = t * 16 + ((l >> 4) << 2);
            float4 bias = *(const float4*)(lb + j);
            float4 o;
            o.x = acc[t][0] + bias.x;
            o.y = acc[t][1] + bias.y;
            o.z = acc[t][2] + bias.z;
            o.w = acc[t][3] + bias.w;
            *(float4*)(h0 + (size_t)row * HID + j) = o;
        }
    }
}

// ---------------- per-layer projection via MFMA bf16 (operand-swapped) ----------------
// Block: 512 threads = 8 waves, covers 32 rows.
// Wave w: rows r0 = blk*32 + (w&1)*16, cols [c0, c0+208), c0 = (w>>1)*208.
// Lane l: h-row = r0 + (l&15); per tile t, j = c0 + 16t + (l>>4)*4 + [0..4).
// Stores: one float4 (qs) or ushort4 (kvpack) per tile -> coalesced.

__global__ __launch_bounds__(512) void proj_kernel(const float* __restrict__ h,
                                                   const ushort* __restrict__ Wt,
                                                   const float* __restrict__ bias_cat,
                                                   float* __restrict__ qs,
                                                   ushort* __restrict__ kvpack) {
    int tid = threadIdx.x;
    int w = tid >> 6, l = tid & 63;
    int r0 = blockIdx.x * 32 + (w & 1) * 16;
    int c0 = (w >> 1) * 208;
    int row = r0 + (l & 15);
    int koff = (l >> 4) * 8;

    short8 a[2];
#pragma unroll
    for (int m = 0; m < 2; ++m) {
        const float* hp = h + (size_t)row * HID + m * 32 + koff;
        float4 f0 = *(const float4*)hp;
        float4 f1 = *(const float4*)(hp + 4);
        ushort8 u;
        u[0] = f2bf(f0.x); u[1] = f2bf(f0.y); u[2] = f2bf(f0.z); u[3] = f2bf(f0.w);
        u[4] = f2bf(f1.x); u[5] = f2bf(f1.y); u[6] = f2bf(f1.z); u[7] = f2bf(f1.w);
        a[m] = __builtin_bit_cast(short8, u);
    }

    f32x4 acc[13];
#pragma unroll
    for (int t = 0; t < 13; ++t) acc[t] = (f32x4){0.f, 0.f, 0.f, 0.f};

    const ushort* wb = Wt + ((size_t)(c0 + (l & 15))) * HID + koff;
#pragma unroll
    for (int t = 0; t < 13; ++t) {
        short8 b0 = *(const short8*)(wb + (size_t)t * 16 * HID);
        short8 b1 = *(const short8*)(wb + (size_t)t * 16 * HID + 32);
        // swapped: A = weight frag, B = h frag
        acc[t] = __builtin_amdgcn_mfma_f32_16x16x32_bf16(b0, a[0], acc[t], 0, 0, 0);
        acc[t] = __builtin_amdgcn_mfma_f32_16x16x32_bf16(b1, a[1], acc[t], 0, 0, 0);
    }

#pragma unroll
    for (int t = 0; t < 13; ++t) {
        int j = c0 + t * 16 + ((l >> 4) << 2);
        float4 bias = *(const float4*)(bias_cat + j);
        float4 o;
        o.x = acc[t][0] + bias.x;
        o.y = acc[t][1] + bias.y;
        o.z = acc[t][2] + bias.z;
        o.w = acc[t][3] + bias.w;
        if (j < 256) {
            *(float4*)(qs + (size_t)row * QSS + j) = o;
        } else if (j < 768) {
            int pout = j - 256;   // permuted layout: store position == column
            ushort4v u4;
            u4[0] = f2bf(o.x); u4[1] = f2bf(o.y); u4[2] = f2bf(o.z); u4[3] = f2bf(o.w);
            *(ushort4v*)(kvpack + (size_t)row * 512 + pout) = u4;
        } else {
            *(float4*)(qs + (size_t)row * QSS + 256 + (j - 768)) = o;
        }
    }
}

// ---------------- per-node edge attention (one wave per node) ----------------
// lane = hh*16 + c16; lane's 16B kvpack load holds its k4 (bf16) and v4 (bf16).
// 2-deep prefetch (high occupancy), exp2 domain, rescale only on new max.

__global__ __launch_bounds__(256) void edge_kernel(const float* __restrict__ qs,
                                                   const ushort8* __restrict__ kvp,
                                                   const int* __restrict__ offs,
                                                   const int* __restrict__ csr,
                                                   float* __restrict__ hout) {
    int wave = threadIdx.x >> 6;
    int lane = threadIdx.x & 63;
    int node = blockIdx.x * 4 + wave;
    if (node >= N_NODES) return;
    int hh = lane >> 4;
    int cb = (lane & 15) * 4;

    const float* nb = qs + (size_t)node * QSS;
    float4 q = *(const float4*)(nb + hh * 64 + cb);

    const float SCL = 0.125f * 1.44269504088896340736f;  // 1/sqrt(64) * log2(e)

    float m = -INFINITY, l = 0.f;
    float4 acc = make_float4(0.f, 0.f, 0.f, 0.f);

    int e0 = offs[node], e1 = offs[node + 1];
    int cnt = e1 - e0;

    ushort8 cur = (ushort8)(0);
    ushort8 nxt = (ushort8)(0);
    if (cnt > 0) cur = kvp[(size_t)csr[e0] * 64 + lane];
    if (cnt > 1) nxt = kvp[(size_t)csr[e0 + 1] * 64 + lane];

    for (int i = 0; i < cnt; ++i) {
        ushort8 u = cur;
        cur = nxt;
        if (i + 2 < cnt) nxt = kvp[(size_t)csr[e0 + i + 2] * 64 + lane];

        float p = q.x * bf2f(u[0]) + q.y * bf2f(u[1]) + q.z * bf2f(u[2]) + q.w * bf2f(u[3]);
        p += __shfl_xor(p, 1);
        p += __shfl_xor(p, 2);
        p += __shfl_xor(p, 4);
        p += __shfl_xor(p, 8);
        float alpha = p * SCL;              // log2-domain logit
        if (__any(alpha > m)) {
            float nm = fmaxf(m, alpha);
            float sc = exp2f(m - nm);
            l *= sc; acc.x *= sc; acc.y *= sc; acc.z *= sc; acc.w *= sc;
            m = nm;
        }
        float pe = exp2f(alpha - m);
        l += pe;
        acc.x += pe * bf2f(u[4]);
        acc.y += pe * bf2f(u[5]);
        acc.z += pe * bf2f(u[6]);
        acc.w += pe * bf2f(u[7]);
    }

    float inv = (l > 0.f) ? (1.f / l) : 0.f;
    float4 r;
    r.x = acc.x * inv;
    r.y = acc.y * inv;
    r.z = acc.z * inv;
    r.w = acc.w * inv;
    r.x += __shfl_xor(r.x, 16); r.x += __shfl_xor(r.x, 32);
    r.y += __shfl_xor(r.y, 16); r.y += __shfl_xor(r.y, 32);
    r.z += __shfl_xor(r.z, 16); r.z += __shfl_xor(r.z, 32);
    r.w += __shfl_xor(r.w, 16); r.w += __shfl_xor(r.w, 32);

    if (hh == 0) {
        float4 s = *(const float4*)(nb + 256 + cb);
        float4 o;
        o.x = fmaxf(r.x * 0.25f + s.x, 0.f);
        o.y = fmaxf(r.y * 0.25f + s.y, 0.f);
        o.z = fmaxf(r.z * 0.25f + s.z, 0.f);
        o.w = fmaxf(r.w * 0.25f + s.w, 0.f);
        *(float4*)(hout + (size_t)node * HID + cb) = o;
    }
}

// ---------------- global add pool ----------------

__global__ __launch_bounds__(256) void pool_kernel(const float* __restrict__ h,
                                                   const int* __restrict__ batch,
                                                   float* __restrict__ out) {
    int g = blockIdx.x;
    int lo = 0, hi = N_NODES;
    while (lo < hi) { int mid = (lo + hi) >> 1; if (batch[mid] < g) lo = mid + 1; else hi = mid; }
    int start = lo;
    hi = N_NODES;
    while (lo < hi) { int mid = (lo + hi) >> 1; if (batch[mid] < g + 1) lo = mid + 1; else hi = mid; }
    int end = lo;
    int c = threadIdx.x & 63;
    int sub = threadIdx.x >> 6;
    float acc = 0.f;
    for (int i = start + sub; i < end; i += 4) acc += h[(size_t)i * HID + c];
    __shared__ float lds[4][64];
    lds[sub][c] = acc;
    __syncthreads();
    if (sub == 0) out[g * HID + c] = lds[0][c] + lds[1][c] + lds[2][c] + lds[3][c];
}

// ---------------- launch ----------------

extern "C" void kernel_launch(void* const* d_in, const int* in_sizes, int n_in,
                              void* d_out, int out_size, void* d_ws, size_t ws_size,
                              hipStream_t stream) {
    const float* x    = (const float*)d_in[0];
    const int*   edge = (const int*)d_in[1];
    const int*   batch= (const int*)d_in[2];
    const float* linW = (const float*)d_in[3];
    const float* linb = (const float*)d_in[4];
    const float* Wq   = (const float*)d_in[5];
    const float* bq   = (const float*)d_in[6];
    const float* Wk   = (const float*)d_in[7];
    const float* bk   = (const float*)d_in[8];
    const float* Wv   = (const float*)d_in[9];
    const float* bv   = (const float*)d_in[10];
    const float* Ws   = (const float*)d_in[11];
    const float* bs   = (const float*)d_in[12];
    float* out = (float*)d_out;

    const int* src = edge;
    const int* dst = edge + N_EDGES;

    float* h0  = (float*)d_ws;                                   // N*64
    float* h1  = h0 + (size_t)N_NODES * HID;                     // N*64
    float* qs  = h1 + (size_t)N_NODES * HID;                     // N*320
    ushort* kvpack = (ushort*)(qs + (size_t)N_NODES * QSS);      // N*512 ushort
    int* counts = (int*)(kvpack + (size_t)N_NODES * 512);
    int* offs   = counts + N_NODES;
    int* cursor = offs + N_NODES + 1;
    int* csr    = cursor + N_NODES;
    int* bsum   = csr + N_EDGES;
    int* bexcl  = bsum + 128;
    ushort* Wt3 = (ushort*)(bexcl + 128);                        // 3*832*64 ushort
    float* bias3 = (float*)(Wt3 + 3 * 832 * 64);                 // 3*832 f32
    ushort* Wlt = (ushort*)(bias3 + 3 * 832);                    // 64*128 ushort

    const int NB = (N_NODES + 255) / 256;   // 79

    // CSR build (dst is fixed across layers)
    hipMemsetAsync(counts, 0, N_NODES * sizeof(int), stream);
    hist_kernel<<<(N_EDGES + 255) / 256, 256, 0, stream>>>(dst, counts, N_EDGES);
    blocksum_kernel<<<NB, 256, 0, stream>>>(counts, bsum, N_NODES);
    scanb_kernel<<<1, 128, 0, stream>>>(bsum, bexcl, NB);
    expand_kernel<<<NB, 256, 0, stream>>>(counts, bexcl, offs, cursor, N_NODES);
    scatter_kernel<<<(N_EDGES + 255) / 256, 256, 0, stream>>>(src, dst, cursor, csr, N_EDGES);

    // one-shot weight conversion (3 layers + input linear)
    wcvt_all_kernel<<<(3 * 832 * 64 + 64 * DIM_IN + 255) / 256, 256, 0, stream>>>(
        Wq, bq, Wk, bk, Wv, bv, Ws, bs, linW, Wt3, bias3, Wlt);

    // input linear (MFMA)
    lin_kernel<<<(N_NODES + 63) / 64, 256, 0, stream>>>(x, Wlt, linb, h0);

    float* hc = h0;
    float* hn = h1;
    for (int l = 0; l < LAYERS; ++l) {
        proj_kernel<<<N_NODES / 32, 512, 0, stream>>>(hc,
            Wt3 + (size_t)l * 832 * 64, bias3 + (size_t)l * 832, qs, kvpack);
        edge_kernel<<<N_NODES / 4, 256, 0, stream>>>(qs, (const ushort8*)kvpack, offs, csr, hn);
        float* t = hc; hc = hn; hn = t;
    }

    pool_kernel<<<GRAPHS, 256, 0, stream>>>(hc, batch, out);
}